// Round 1
// baseline (704.053 us; speedup 1.0000x reference)
//
#include <hip/hip_runtime.h>
#include <cstddef>

#define NN 100000
#define EE 1600000
#define FEATD 128
#define HIDD 64
#define OUTD 16

static inline int ceil_div(int a, int b){ return (a + b - 1) / b; }

// ---------------- e = mean(x_emb, axis=1) ----------------
__global__ void compute_e_kernel(const float* __restrict__ x_emb, float* __restrict__ e){
  int q = blockIdx.x * blockDim.x + threadIdx.x;     // quad index over N*64/4
  if (q >= NN * 16) return;
  int n = q >> 4, cq = q & 15;
  const float4* p = (const float4*)x_emb;
  float4 a = p[(size_t)n * 32 + cq];
  float4 b = p[(size_t)n * 32 + 16 + cq];
  float4 r;
  r.x = 0.5f * (a.x + b.x); r.y = 0.5f * (a.y + b.y);
  r.z = 0.5f * (a.z + b.z); r.w = 0.5f * (a.w + b.w);
  ((float4*)e)[(size_t)n * 16 + cq] = r;
}

// ---------------- CSR build ----------------
__global__ void deg_kernel(const int* __restrict__ dst, int* __restrict__ deg){
  int i = blockIdx.x * blockDim.x + threadIdx.x;
  if (i < EE) atomicAdd(&deg[dst[i]], 1);
}

__global__ void scan1_kernel(const int* __restrict__ deg, int* __restrict__ bsum){
  __shared__ int s[256];
  int t = threadIdx.x; int i = blockIdx.x * 256 + t;
  s[t] = (i < NN) ? deg[i] : 0;
  __syncthreads();
  for (int off = 128; off > 0; off >>= 1){
    if (t < off) s[t] += s[t + off];
    __syncthreads();
  }
  if (t == 0) bsum[blockIdx.x] = s[0];
}

__global__ void scan2_kernel(int* bsum, int nb){
  if (threadIdx.x == 0 && blockIdx.x == 0){
    int run = 0;
    for (int i = 0; i < nb; i++){ int v = bsum[i]; bsum[i] = run; run += v; }
  }
}

__global__ void scan3_kernel(const int* __restrict__ deg, const int* __restrict__ bsum,
                             int* __restrict__ rs){
  __shared__ int s[256];
  int t = threadIdx.x; int i = blockIdx.x * 256 + t;
  int v = (i < NN) ? deg[i] : 0;
  s[t] = v; __syncthreads();
  for (int off = 1; off < 256; off <<= 1){
    int x = (t >= off) ? s[t - off] : 0;
    __syncthreads();
    s[t] += x;
    __syncthreads();
  }
  if (i < NN) rs[i] = bsum[blockIdx.x] + s[t] - v;   // exclusive prefix
}

__global__ void fill_kernel(const int* __restrict__ src, const int* __restrict__ dst,
                            const int* __restrict__ rs, int* __restrict__ cur,
                            int* __restrict__ ssrc){
  int i = blockIdx.x * blockDim.x + threadIdx.x;
  if (i >= EE) return;
  int d = dst[i];
  int pos = atomicAdd(&cur[d], 1);
  ssrc[rs[d] + pos] = src[i];
}

// ---------------- fp32 GEMM: C[M,64] = A[M,K] @ W[64,K]^T (+bias) ----------------
template<int K>
__global__ __launch_bounds__(256) void gemm64_kernel(
    const float* __restrict__ A, const float* __restrict__ W,
    const float* __restrict__ bias, float* __restrict__ C, int M){
  __shared__ float As[64][K + 1];
  __shared__ float Bs[64][K + 1];
  const int t = threadIdx.x;
  const int row0 = blockIdx.x * 64;
  constexpr int KQ = K / 4;
  for (int idx = t; idx < 64 * KQ; idx += 256){
    int j = idx / KQ, kq = idx % KQ;
    float4 v = ((const float4*)W)[j * KQ + kq];
    Bs[j][kq*4+0] = v.x; Bs[j][kq*4+1] = v.y; Bs[j][kq*4+2] = v.z; Bs[j][kq*4+3] = v.w;
  }
  for (int idx = t; idx < 64 * KQ; idx += 256){
    int n = idx / KQ, kq = idx % KQ;
    int row = row0 + n;
    float4 v = make_float4(0.f, 0.f, 0.f, 0.f);
    if (row < M) v = ((const float4*)A)[(size_t)row * KQ + kq];
    As[n][kq*4+0] = v.x; As[n][kq*4+1] = v.y; As[n][kq*4+2] = v.z; As[n][kq*4+3] = v.w;
  }
  __syncthreads();
  const int tx = t & 15, ty = t >> 4;
  float acc[4][4] = {};
  #pragma unroll 4
  for (int k = 0; k < K; k++){
    float a[4], b[4];
    #pragma unroll
    for (int i = 0; i < 4; i++){ a[i] = As[ty*4 + i][k]; b[i] = Bs[tx*4 + i][k]; }
    #pragma unroll
    for (int i = 0; i < 4; i++)
      #pragma unroll
      for (int j = 0; j < 4; j++) acc[i][j] = fmaf(a[i], b[j], acc[i][j]);
  }
  #pragma unroll
  for (int i = 0; i < 4; i++){
    int row = row0 + ty*4 + i;
    if (row < M){
      int col = tx * 4;
      float4 v = make_float4(acc[i][0], acc[i][1], acc[i][2], acc[i][3]);
      if (bias){ v.x += bias[col]; v.y += bias[col+1]; v.z += bias[col+2]; v.w += bias[col+3]; }
      ((float4*)C)[((size_t)row * 64 + col) >> 2] = v;
    }
  }
}

// ---------------- fp32 GEMM: C[M,16] = A1@W1^T (+ A2@W2^T) (+ b1 + b2) ----------------
template<bool DUAL>
__global__ __launch_bounds__(256) void gemm16_kernel(
    const float* __restrict__ A1, const float* __restrict__ W1,
    const float* __restrict__ A2, const float* __restrict__ W2,
    const float* __restrict__ b1, const float* __restrict__ b2,
    float* __restrict__ C, int M){
  __shared__ float As1[64][65];
  __shared__ float As2[64][65];
  __shared__ float Ws1[16][65];
  __shared__ float Ws2[16][65];
  __shared__ float bs[16];
  const int t = threadIdx.x;
  const int row0 = blockIdx.x * 64;
  {
    int j = t >> 4, kq = t & 15;   // 256 threads cover 16x16 quads exactly
    float4 v = ((const float4*)W1)[j * 16 + kq];
    Ws1[j][kq*4+0] = v.x; Ws1[j][kq*4+1] = v.y; Ws1[j][kq*4+2] = v.z; Ws1[j][kq*4+3] = v.w;
    if (DUAL){
      float4 u = ((const float4*)W2)[j * 16 + kq];
      Ws2[j][kq*4+0] = u.x; Ws2[j][kq*4+1] = u.y; Ws2[j][kq*4+2] = u.z; Ws2[j][kq*4+3] = u.w;
    }
  }
  if (t < 16){
    float bv = 0.f;
    if (b1) bv += b1[t];
    if (b2) bv += b2[t];
    bs[t] = bv;
  }
  for (int idx = t; idx < 64 * 16; idx += 256){
    int n = idx >> 4, kq = idx & 15;
    int row = row0 + n;
    float4 v = make_float4(0.f,0.f,0.f,0.f), u = make_float4(0.f,0.f,0.f,0.f);
    if (row < M){
      v = ((const float4*)A1)[(size_t)row * 16 + kq];
      if (DUAL) u = ((const float4*)A2)[(size_t)row * 16 + kq];
    }
    As1[n][kq*4+0] = v.x; As1[n][kq*4+1] = v.y; As1[n][kq*4+2] = v.z; As1[n][kq*4+3] = v.w;
    if (DUAL){
      As2[n][kq*4+0] = u.x; As2[n][kq*4+1] = u.y; As2[n][kq*4+2] = u.z; As2[n][kq*4+3] = u.w;
    }
  }
  __syncthreads();
  const int n = t >> 2, jq = t & 3;
  float acc[4] = {};
  #pragma unroll 4
  for (int k = 0; k < 64; k++){
    float a1 = As1[n][k];
    #pragma unroll
    for (int j = 0; j < 4; j++) acc[j] = fmaf(a1, Ws1[jq*4 + j][k], acc[j]);
    if (DUAL){
      float a2 = As2[n][k];
      #pragma unroll
      for (int j = 0; j < 4; j++) acc[j] = fmaf(a2, Ws2[jq*4 + j][k], acc[j]);
    }
  }
  int row = row0 + n;
  if (row < M){
    float4 v = make_float4(acc[0] + bs[jq*4+0], acc[1] + bs[jq*4+1],
                           acc[2] + bs[jq*4+2], acc[3] + bs[jq*4+3]);
    ((float4*)C)[(size_t)row * 4 + jq] = v;
  }
}

// ---------------- layer-0 aggregation: wave per dst, lane = feature ----------------
__global__ void agg0_kernel(const float* __restrict__ y0, const float* __restrict__ r0,
                            const float* __restrict__ e0, const float* __restrict__ bl0,
                            const int* __restrict__ rs, const int* __restrict__ deg,
                            const int* __restrict__ ssrc, float* __restrict__ h){
  int g = blockIdx.x * blockDim.x + threadIdx.x;
  int node = g >> 6, lane = g & 63;
  if (node >= NN) return;
  int start = rs[node], cnt = deg[node];
  float acc = 0.f;
  for (int i = 0; i < cnt; i++){
    int s = ssrc[start + i];
    acc += y0[(size_t)s * 64 + lane];
  }
  float inv = 1.0f / (float)(cnt > 1 ? cnt : 1);
  float v = acc * inv + r0[(size_t)node * 64 + lane] + e0[(size_t)node * 64 + lane] + bl0[lane];
  h[(size_t)node * 64 + lane] = v > 0.f ? v : 0.f;
}

// ---------------- layer-1 aggregation: 16 lanes per dst ----------------
__global__ void agg1_kernel(const float* __restrict__ y1, const int* __restrict__ rs,
                            const int* __restrict__ deg, const int* __restrict__ ssrc,
                            float* __restrict__ outp){
  int g = blockIdx.x * blockDim.x + threadIdx.x;
  if (g >= NN * 16) return;
  int node = g >> 4, j = g & 15;
  int start = rs[node], cnt = deg[node];
  float acc = 0.f;
  for (int i = 0; i < cnt; i++){
    int s = ssrc[start + i];
    acc += y1[(size_t)s * 16 + j];
  }
  float inv = 1.0f / (float)(cnt > 1 ? cnt : 1);
  outp[g] += acc * inv;
}

extern "C" void kernel_launch(void* const* d_in, const int* in_sizes, int n_in,
                              void* d_out, int out_size, void* d_ws, size_t ws_size,
                              hipStream_t stream){
  (void)in_sizes; (void)n_in; (void)out_size; (void)ws_size;
  const float* x_feat = (const float*)d_in[0];
  const float* x_emb  = (const float*)d_in[1];
  const int*   ei     = (const int*)d_in[2];
  const float* Wl0 = (const float*)d_in[3];
  const float* bl0 = (const float*)d_in[4];
  const float* Wr0 = (const float*)d_in[5];
  const float* We0 = (const float*)d_in[6];
  const float* be0 = (const float*)d_in[7];
  const float* Wl1 = (const float*)d_in[8];
  const float* bl1 = (const float*)d_in[9];
  const float* Wr1 = (const float*)d_in[10];
  const float* We1 = (const float*)d_in[11];
  const float* be1 = (const float*)d_in[12];
  float* out = (float*)d_out;

  // workspace layout (~110 MB)
  char* w = (char*)d_ws;
  float* e_buf = (float*)w;  w += sizeof(float) * (size_t)NN * 64;   // reused as h
  float* y0    = (float*)w;  w += sizeof(float) * (size_t)NN * 64;   // reused as y1
  float* r0    = (float*)w;  w += sizeof(float) * (size_t)NN * 64;
  float* e0    = (float*)w;  w += sizeof(float) * (size_t)NN * 64;
  int* deg     = (int*)w;    w += sizeof(int) * NN;
  int* rs      = (int*)w;    w += sizeof(int) * NN;
  int* cur     = (int*)w;    w += sizeof(int) * NN;
  int* bsum    = (int*)w;    w += sizeof(int) * 1024;
  int* ssrc    = (int*)w;    w += sizeof(int) * (size_t)EE;

  const int* srcp = ei;
  const int* dstp = ei + EE;

  hipMemsetAsync(deg, 0, sizeof(int) * NN, stream);
  hipMemsetAsync(cur, 0, sizeof(int) * NN, stream);

  compute_e_kernel<<<ceil_div(NN * 16, 256), 256, 0, stream>>>(x_emb, e_buf);
  deg_kernel<<<ceil_div(EE, 256), 256, 0, stream>>>(dstp, deg);
  int nb = ceil_div(NN, 256);   // 391
  scan1_kernel<<<nb, 256, 0, stream>>>(deg, bsum);
  scan2_kernel<<<1, 64, 0, stream>>>(bsum, nb);
  scan3_kernel<<<nb, 256, 0, stream>>>(deg, bsum, rs);
  fill_kernel<<<ceil_div(EE, 256), 256, 0, stream>>>(srcp, dstp, rs, cur, ssrc);

  // layer 0 node-parallel transforms
  gemm64_kernel<128><<<ceil_div(NN, 64), 256, 0, stream>>>(x_feat, Wl0, nullptr, y0, NN);
  gemm64_kernel<128><<<ceil_div(NN, 64), 256, 0, stream>>>(x_feat, Wr0, nullptr, r0, NN);
  gemm64_kernel<64><<<ceil_div(NN, 64), 256, 0, stream>>>(e_buf, We0, be0, e0, NN);

  // h = relu(agg(y0)/deg + r0 + e0 + bl0); h aliases e_buf (e consumed above)
  float* h = e_buf;
  agg0_kernel<<<ceil_div(NN * 64, 256), 256, 0, stream>>>(y0, r0, e0, bl0, rs, deg, ssrc, h);

  // layer 1
  float* y1 = y0;  // y0 dead after agg0
  gemm16_kernel<false><<<ceil_div(NN, 64), 256, 0, stream>>>(h, Wl1, nullptr, nullptr,
                                                             nullptr, nullptr, y1, NN);
  gemm16_kernel<true><<<ceil_div(NN, 64), 256, 0, stream>>>(h, Wr1, e0, We1,
                                                            bl1, be1, out, NN);
  agg1_kernel<<<ceil_div(NN * 16, 256), 256, 0, stream>>>(y1, rs, deg, ssrc, out);
}

// Round 2
// 524.177 us; speedup vs baseline: 1.3432x; 1.3432x over previous
//
#include <hip/hip_runtime.h>
#include <cstddef>

#define NN 100000
#define EE 1600000
#define FEATD 128
#define HIDD 64
#define OUTD 16

static inline int ceil_div(int a, int b){ return (a + b - 1) / b; }

// ---------------- e = mean(x_emb, axis=1) ----------------
__global__ void compute_e_kernel(const float* __restrict__ x_emb, float* __restrict__ e){
  int q = blockIdx.x * blockDim.x + threadIdx.x;     // quad index over N*64/4
  if (q >= NN * 16) return;
  int n = q >> 4, cq = q & 15;
  const float4* p = (const float4*)x_emb;
  float4 a = p[(size_t)n * 32 + cq];
  float4 b = p[(size_t)n * 32 + 16 + cq];
  float4 r;
  r.x = 0.5f * (a.x + b.x); r.y = 0.5f * (a.y + b.y);
  r.z = 0.5f * (a.z + b.z); r.w = 0.5f * (a.w + b.w);
  ((float4*)e)[(size_t)n * 16 + cq] = r;
}

// ---------------- CSR build ----------------
__global__ void deg_kernel(const int* __restrict__ dst, int* __restrict__ deg){
  int i = blockIdx.x * blockDim.x + threadIdx.x;
  if (i < EE) atomicAdd(&deg[dst[i]], 1);
}

__global__ void scan1_kernel(const int* __restrict__ deg, int* __restrict__ bsum){
  __shared__ int s[256];
  int t = threadIdx.x; int i = blockIdx.x * 256 + t;
  s[t] = (i < NN) ? deg[i] : 0;
  __syncthreads();
  for (int off = 128; off > 0; off >>= 1){
    if (t < off) s[t] += s[t + off];
    __syncthreads();
  }
  if (t == 0) bsum[blockIdx.x] = s[0];
}

// parallel single-block exclusive scan over nb (<=512) block sums
__global__ void scan2_kernel(int* bsum, int nb){
  __shared__ int s[512];
  int t = threadIdx.x;
  int v = (t < nb) ? bsum[t] : 0;
  s[t] = v;
  __syncthreads();
  for (int off = 1; off < 512; off <<= 1){
    int x = (t >= off) ? s[t - off] : 0;
    __syncthreads();
    s[t] += x;
    __syncthreads();
  }
  if (t < nb) bsum[t] = s[t] - v;   // exclusive prefix of block sums
}

__global__ void scan3_kernel(const int* __restrict__ deg, const int* __restrict__ bsum,
                             int* __restrict__ rs){
  __shared__ int s[256];
  int t = threadIdx.x; int i = blockIdx.x * 256 + t;
  int v = (i < NN) ? deg[i] : 0;
  s[t] = v; __syncthreads();
  for (int off = 1; off < 256; off <<= 1){
    int x = (t >= off) ? s[t - off] : 0;
    __syncthreads();
    s[t] += x;
    __syncthreads();
  }
  if (i < NN) rs[i] = bsum[blockIdx.x] + s[t] - v;   // exclusive prefix
}

__global__ void fill_kernel(const int* __restrict__ src, const int* __restrict__ dst,
                            const int* __restrict__ rs, int* __restrict__ cur,
                            int* __restrict__ ssrc){
  int i = blockIdx.x * blockDim.x + threadIdx.x;
  if (i >= EE) return;
  int d = dst[i];
  int pos = atomicAdd(&cur[d], 1);
  ssrc[rs[d] + pos] = src[i];
}

// ---------------- dual fp32 GEMM: C1 = A@W1^T, C2 = A@W2^T  (A [M,128], W [64,128]) ----------------
__global__ __launch_bounds__(256) void gemm64_dual_kernel(
    const float* __restrict__ A, const float* __restrict__ W1, const float* __restrict__ W2,
    float* __restrict__ C1, float* __restrict__ C2, int M){
  __shared__ float As[64][129];
  __shared__ float B1[64][65];
  __shared__ float B2[64][65];
  const int t = threadIdx.x;
  const int row0 = blockIdx.x * 64;
  // As: 64 rows x 128 cols = 2048 quads
  for (int idx = t; idx < 64 * 32; idx += 256){
    int n = idx >> 5, kq = idx & 31;
    int row = row0 + n;
    float4 v = (row < M) ? ((const float4*)A)[(size_t)row * 32 + kq]
                         : make_float4(0.f, 0.f, 0.f, 0.f);
    As[n][kq*4+0] = v.x; As[n][kq*4+1] = v.y; As[n][kq*4+2] = v.z; As[n][kq*4+3] = v.w;
  }
  const int tx = t & 15, ty = t >> 4;
  float acc1[4][4] = {}; float acc2[4][4] = {};
  for (int kb = 0; kb < 2; kb++){
    __syncthreads();  // kb=0: As ready; kb=1: everyone done with previous B halves
    for (int idx = t; idx < 64 * 16; idx += 256){
      int j = idx >> 4, kq = idx & 15;
      float4 v1 = ((const float4*)W1)[j * 32 + kb * 16 + kq];
      float4 v2 = ((const float4*)W2)[j * 32 + kb * 16 + kq];
      B1[j][kq*4+0] = v1.x; B1[j][kq*4+1] = v1.y; B1[j][kq*4+2] = v1.z; B1[j][kq*4+3] = v1.w;
      B2[j][kq*4+0] = v2.x; B2[j][kq*4+1] = v2.y; B2[j][kq*4+2] = v2.z; B2[j][kq*4+3] = v2.w;
    }
    __syncthreads();
    #pragma unroll 4
    for (int k = 0; k < 64; k++){
      float a[4], b1[4], b2[4];
      #pragma unroll
      for (int i = 0; i < 4; i++){
        a[i]  = As[ty*4 + i][kb*64 + k];
        b1[i] = B1[tx*4 + i][k];
        b2[i] = B2[tx*4 + i][k];
      }
      #pragma unroll
      for (int i = 0; i < 4; i++)
        #pragma unroll
        for (int j = 0; j < 4; j++){
          acc1[i][j] = fmaf(a[i], b1[j], acc1[i][j]);
          acc2[i][j] = fmaf(a[i], b2[j], acc2[i][j]);
        }
    }
  }
  #pragma unroll
  for (int i = 0; i < 4; i++){
    int row = row0 + ty*4 + i;
    if (row < M){
      ((float4*)C1)[(size_t)row * 16 + tx] = make_float4(acc1[i][0], acc1[i][1], acc1[i][2], acc1[i][3]);
      ((float4*)C2)[(size_t)row * 16 + tx] = make_float4(acc2[i][0], acc2[i][1], acc2[i][2], acc2[i][3]);
    }
  }
}

// ---------------- fp32 GEMM: C[M,64] = A[M,K] @ W[64,K]^T (+bias) ----------------
template<int K>
__global__ __launch_bounds__(256) void gemm64_kernel(
    const float* __restrict__ A, const float* __restrict__ W,
    const float* __restrict__ bias, float* __restrict__ C, int M){
  __shared__ float As[64][K + 1];
  __shared__ float Bs[64][K + 1];
  const int t = threadIdx.x;
  const int row0 = blockIdx.x * 64;
  constexpr int KQ = K / 4;
  for (int idx = t; idx < 64 * KQ; idx += 256){
    int j = idx / KQ, kq = idx % KQ;
    float4 v = ((const float4*)W)[j * KQ + kq];
    Bs[j][kq*4+0] = v.x; Bs[j][kq*4+1] = v.y; Bs[j][kq*4+2] = v.z; Bs[j][kq*4+3] = v.w;
  }
  for (int idx = t; idx < 64 * KQ; idx += 256){
    int n = idx / KQ, kq = idx % KQ;
    int row = row0 + n;
    float4 v = make_float4(0.f, 0.f, 0.f, 0.f);
    if (row < M) v = ((const float4*)A)[(size_t)row * KQ + kq];
    As[n][kq*4+0] = v.x; As[n][kq*4+1] = v.y; As[n][kq*4+2] = v.z; As[n][kq*4+3] = v.w;
  }
  __syncthreads();
  const int tx = t & 15, ty = t >> 4;
  float acc[4][4] = {};
  #pragma unroll 4
  for (int k = 0; k < K; k++){
    float a[4], b[4];
    #pragma unroll
    for (int i = 0; i < 4; i++){ a[i] = As[ty*4 + i][k]; b[i] = Bs[tx*4 + i][k]; }
    #pragma unroll
    for (int i = 0; i < 4; i++)
      #pragma unroll
      for (int j = 0; j < 4; j++) acc[i][j] = fmaf(a[i], b[j], acc[i][j]);
  }
  #pragma unroll
  for (int i = 0; i < 4; i++){
    int row = row0 + ty*4 + i;
    if (row < M){
      int col = tx * 4;
      float4 v = make_float4(acc[i][0], acc[i][1], acc[i][2], acc[i][3]);
      if (bias){ v.x += bias[col]; v.y += bias[col+1]; v.z += bias[col+2]; v.w += bias[col+3]; }
      ((float4*)C)[((size_t)row * 64 + col) >> 2] = v;
    }
  }
}

// ---------- dual 16-col GEMM: Y1 = H@Wl1^T ; Out = H@Wr1^T + E@We1^T + bl1 + be1 ----------
__global__ __launch_bounds__(256) void gemm16_dual_kernel(
    const float* __restrict__ H, const float* __restrict__ E,
    const float* __restrict__ Wl1, const float* __restrict__ Wr1, const float* __restrict__ We1,
    const float* __restrict__ bl1, const float* __restrict__ be1,
    float* __restrict__ Y1, float* __restrict__ Out, int M){
  __shared__ float Hs[64][65];
  __shared__ float Es[64][65];
  __shared__ float Wls[16][65];
  __shared__ float Wrs[16][65];
  __shared__ float Wes[16][65];
  __shared__ float bs[16];
  const int t = threadIdx.x;
  const int row0 = blockIdx.x * 64;
  {
    int j = t >> 4, kq = t & 15;   // 256 threads cover 16x16 quads exactly
    float4 a = ((const float4*)Wl1)[j * 16 + kq];
    float4 b = ((const float4*)Wr1)[j * 16 + kq];
    float4 c = ((const float4*)We1)[j * 16 + kq];
    Wls[j][kq*4+0]=a.x; Wls[j][kq*4+1]=a.y; Wls[j][kq*4+2]=a.z; Wls[j][kq*4+3]=a.w;
    Wrs[j][kq*4+0]=b.x; Wrs[j][kq*4+1]=b.y; Wrs[j][kq*4+2]=b.z; Wrs[j][kq*4+3]=b.w;
    Wes[j][kq*4+0]=c.x; Wes[j][kq*4+1]=c.y; Wes[j][kq*4+2]=c.z; Wes[j][kq*4+3]=c.w;
  }
  if (t < 16) bs[t] = bl1[t] + be1[t];
  for (int idx = t; idx < 64 * 16; idx += 256){
    int n = idx >> 4, kq = idx & 15;
    int row = row0 + n;
    float4 v = make_float4(0.f,0.f,0.f,0.f), u = make_float4(0.f,0.f,0.f,0.f);
    if (row < M){
      v = ((const float4*)H)[(size_t)row * 16 + kq];
      u = ((const float4*)E)[(size_t)row * 16 + kq];
    }
    Hs[n][kq*4+0]=v.x; Hs[n][kq*4+1]=v.y; Hs[n][kq*4+2]=v.z; Hs[n][kq*4+3]=v.w;
    Es[n][kq*4+0]=u.x; Es[n][kq*4+1]=u.y; Es[n][kq*4+2]=u.z; Es[n][kq*4+3]=u.w;
  }
  __syncthreads();
  const int n = t >> 2, jq = t & 3;
  float y[4] = {}, o[4] = {};
  #pragma unroll 4
  for (int k = 0; k < 64; k++){
    float a = Hs[n][k];
    float e = Es[n][k];
    #pragma unroll
    for (int j = 0; j < 4; j++){
      y[j] = fmaf(a, Wls[jq*4 + j][k], y[j]);
      o[j] = fmaf(a, Wrs[jq*4 + j][k], o[j]);
      o[j] = fmaf(e, Wes[jq*4 + j][k], o[j]);
    }
  }
  int row = row0 + n;
  if (row < M){
    ((float4*)Y1)[(size_t)row * 4 + jq] = make_float4(y[0], y[1], y[2], y[3]);
    ((float4*)Out)[(size_t)row * 4 + jq] =
        make_float4(o[0] + bs[jq*4+0], o[1] + bs[jq*4+1], o[2] + bs[jq*4+2], o[3] + bs[jq*4+3]);
  }
}

// ---------------- layer-0 aggregation: 16 lanes/node (float4), 4 nodes/wave, unroll 4 ----------------
__global__ void agg0_kernel(const float4* __restrict__ y0, const float4* __restrict__ r0,
                            const float4* __restrict__ e0, const float* __restrict__ bl0,
                            const int* __restrict__ rs, const int* __restrict__ deg,
                            const int* __restrict__ ssrc, float4* __restrict__ h){
  int g = blockIdx.x * blockDim.x + threadIdx.x;
  if (g >= NN * 16) return;
  int node = g >> 4, lane = g & 15;
  int start = rs[node], cnt = deg[node];
  float4 a0 = make_float4(0.f,0.f,0.f,0.f), a1 = a0, a2 = a0, a3 = a0;
  int i = 0;
  for (; i + 4 <= cnt; i += 4){
    int s0 = ssrc[start+i+0], s1 = ssrc[start+i+1];
    int s2 = ssrc[start+i+2], s3 = ssrc[start+i+3];
    float4 v0 = y0[(size_t)s0 * 16 + lane];
    float4 v1 = y0[(size_t)s1 * 16 + lane];
    float4 v2 = y0[(size_t)s2 * 16 + lane];
    float4 v3 = y0[(size_t)s3 * 16 + lane];
    a0.x += v0.x; a0.y += v0.y; a0.z += v0.z; a0.w += v0.w;
    a1.x += v1.x; a1.y += v1.y; a1.z += v1.z; a1.w += v1.w;
    a2.x += v2.x; a2.y += v2.y; a2.z += v2.z; a2.w += v2.w;
    a3.x += v3.x; a3.y += v3.y; a3.z += v3.z; a3.w += v3.w;
  }
  for (; i < cnt; i++){
    int s = ssrc[start + i];
    float4 v = y0[(size_t)s * 16 + lane];
    a0.x += v.x; a0.y += v.y; a0.z += v.z; a0.w += v.w;
  }
  float4 s;
  s.x = (a0.x + a1.x) + (a2.x + a3.x);
  s.y = (a0.y + a1.y) + (a2.y + a3.y);
  s.z = (a0.z + a1.z) + (a2.z + a3.z);
  s.w = (a0.w + a1.w) + (a2.w + a3.w);
  float inv = 1.0f / (float)(cnt > 1 ? cnt : 1);
  float4 rr = r0[(size_t)node * 16 + lane];
  float4 ee = e0[(size_t)node * 16 + lane];
  float4 bb = ((const float4*)bl0)[lane];
  float4 v;
  v.x = s.x * inv + rr.x + ee.x + bb.x;
  v.y = s.y * inv + rr.y + ee.y + bb.y;
  v.z = s.z * inv + rr.z + ee.z + bb.z;
  v.w = s.w * inv + rr.w + ee.w + bb.w;
  v.x = v.x > 0.f ? v.x : 0.f;
  v.y = v.y > 0.f ? v.y : 0.f;
  v.z = v.z > 0.f ? v.z : 0.f;
  v.w = v.w > 0.f ? v.w : 0.f;
  h[(size_t)node * 16 + lane] = v;
}

// ---------------- layer-1 aggregation: 4 lanes/node (float4), 16 nodes/wave, unroll 2 ----------------
__global__ void agg1_kernel(const float4* __restrict__ y1, const int* __restrict__ rs,
                            const int* __restrict__ deg, const int* __restrict__ ssrc,
                            float4* __restrict__ outp){
  int g = blockIdx.x * blockDim.x + threadIdx.x;
  if (g >= NN * 4) return;
  int node = g >> 2, lane = g & 3;
  int start = rs[node], cnt = deg[node];
  float4 a0 = make_float4(0.f,0.f,0.f,0.f), a1 = a0;
  int i = 0;
  for (; i + 2 <= cnt; i += 2){
    int s0 = ssrc[start+i+0], s1 = ssrc[start+i+1];
    float4 v0 = y1[(size_t)s0 * 4 + lane];
    float4 v1 = y1[(size_t)s1 * 4 + lane];
    a0.x += v0.x; a0.y += v0.y; a0.z += v0.z; a0.w += v0.w;
    a1.x += v1.x; a1.y += v1.y; a1.z += v1.z; a1.w += v1.w;
  }
  if (i < cnt){
    int s = ssrc[start + i];
    float4 v = y1[(size_t)s * 4 + lane];
    a0.x += v.x; a0.y += v.y; a0.z += v.z; a0.w += v.w;
  }
  float inv = 1.0f / (float)(cnt > 1 ? cnt : 1);
  float4 o = outp[(size_t)node * 4 + lane];
  o.x += (a0.x + a1.x) * inv;
  o.y += (a0.y + a1.y) * inv;
  o.z += (a0.z + a1.z) * inv;
  o.w += (a0.w + a1.w) * inv;
  outp[(size_t)node * 4 + lane] = o;
}

extern "C" void kernel_launch(void* const* d_in, const int* in_sizes, int n_in,
                              void* d_out, int out_size, void* d_ws, size_t ws_size,
                              hipStream_t stream){
  (void)in_sizes; (void)n_in; (void)out_size; (void)ws_size;
  const float* x_feat = (const float*)d_in[0];
  const float* x_emb  = (const float*)d_in[1];
  const int*   ei     = (const int*)d_in[2];
  const float* Wl0 = (const float*)d_in[3];
  const float* bl0 = (const float*)d_in[4];
  const float* Wr0 = (const float*)d_in[5];
  const float* We0 = (const float*)d_in[6];
  const float* be0 = (const float*)d_in[7];
  const float* Wl1 = (const float*)d_in[8];
  const float* bl1 = (const float*)d_in[9];
  const float* Wr1 = (const float*)d_in[10];
  const float* We1 = (const float*)d_in[11];
  const float* be1 = (const float*)d_in[12];
  float* out = (float*)d_out;

  // workspace layout (~110 MB)
  char* w = (char*)d_ws;
  float* e_buf = (float*)w;  w += sizeof(float) * (size_t)NN * 64;   // reused as h
  float* y0    = (float*)w;  w += sizeof(float) * (size_t)NN * 64;   // reused as y1
  float* r0    = (float*)w;  w += sizeof(float) * (size_t)NN * 64;
  float* e0    = (float*)w;  w += sizeof(float) * (size_t)NN * 64;
  int* deg     = (int*)w;    w += sizeof(int) * NN;
  int* rs      = (int*)w;    w += sizeof(int) * NN;
  int* cur     = (int*)w;    w += sizeof(int) * NN;
  int* bsum    = (int*)w;    w += sizeof(int) * 1024;
  int* ssrc    = (int*)w;    w += sizeof(int) * (size_t)EE;

  const int* srcp = ei;
  const int* dstp = ei + EE;

  hipMemsetAsync(deg, 0, sizeof(int) * NN, stream);
  hipMemsetAsync(cur, 0, sizeof(int) * NN, stream);

  compute_e_kernel<<<ceil_div(NN * 16, 256), 256, 0, stream>>>(x_emb, e_buf);
  deg_kernel<<<ceil_div(EE, 256), 256, 0, stream>>>(dstp, deg);
  int nb = ceil_div(NN, 256);   // 391
  scan1_kernel<<<nb, 256, 0, stream>>>(deg, bsum);
  scan2_kernel<<<1, 512, 0, stream>>>(bsum, nb);
  scan3_kernel<<<nb, 256, 0, stream>>>(deg, bsum, rs);
  fill_kernel<<<ceil_div(EE, 256), 256, 0, stream>>>(srcp, dstp, rs, cur, ssrc);

  // layer 0 node-parallel transforms: y0 = x@Wl0^T, r0 = x@Wr0^T (shared A pass)
  gemm64_dual_kernel<<<ceil_div(NN, 64), 256, 0, stream>>>(x_feat, Wl0, Wr0, y0, r0, NN);
  gemm64_kernel<64><<<ceil_div(NN, 64), 256, 0, stream>>>(e_buf, We0, be0, e0, NN);

  // h = relu(agg(y0)/deg + r0 + e0 + bl0); h aliases e_buf (e consumed above)
  float* h = e_buf;
  agg0_kernel<<<ceil_div(NN * 16, 256), 256, 0, stream>>>(
      (const float4*)y0, (const float4*)r0, (const float4*)e0, bl0, rs, deg, ssrc, (float4*)h);

  // layer 1: y1 = h@Wl1^T ; out = h@Wr1^T + e0@We1^T + bl1 + be1  (one pass over h)
  float* y1 = y0;  // y0 dead after agg0
  gemm16_dual_kernel<<<ceil_div(NN, 64), 256, 0, stream>>>(h, e0, Wl1, Wr1, We1,
                                                           bl1, be1, y1, out, NN);
  agg1_kernel<<<ceil_div(NN * 4, 256), 256, 0, stream>>>(
      (const float4*)y1, rs, deg, ssrc, (float4*)out);
}

// Round 3
// 432.794 us; speedup vs baseline: 1.6268x; 1.2111x over previous
//
#include <hip/hip_runtime.h>
#include <hip/hip_bf16.h>
#include <cstddef>

#define NN 100000
#define EE 1600000

typedef __attribute__((ext_vector_type(8))) short bf16x8;
typedef __attribute__((ext_vector_type(4))) float f32x4;

static inline int ceil_div(int a, int b){ return (a + b - 1) / b; }

__device__ inline unsigned short f2bf(float f){
  union { float f; unsigned u; } v; v.f = f;
  unsigned r = (v.u + 0x7fff + ((v.u >> 16) & 1)) >> 16;   // RNE
  return (unsigned short)r;
}
__device__ inline float bf2f(unsigned short s){
  union { unsigned u; float f; } v; v.u = ((unsigned)s) << 16;
  return v.f;
}

// ---------------- e = mean(x_emb, axis=1) ----------------
__global__ void compute_e_kernel(const float* __restrict__ x_emb, float* __restrict__ e){
  int q = blockIdx.x * blockDim.x + threadIdx.x;
  if (q >= NN * 16) return;
  int n = q >> 4, cq = q & 15;
  const float4* p = (const float4*)x_emb;
  float4 a = p[(size_t)n * 32 + cq];
  float4 b = p[(size_t)n * 32 + 16 + cq];
  float4 r;
  r.x = 0.5f * (a.x + b.x); r.y = 0.5f * (a.y + b.y);
  r.z = 0.5f * (a.z + b.z); r.w = 0.5f * (a.w + b.w);
  ((float4*)e)[(size_t)n * 16 + cq] = r;
}

// ---------------- CSR build ----------------
__global__ void deg_kernel(const int* __restrict__ dst, int* __restrict__ deg){
  int i = blockIdx.x * blockDim.x + threadIdx.x;
  if (i < EE) atomicAdd(&deg[dst[i]], 1);
}

__global__ void scan1_kernel(const int* __restrict__ deg, int* __restrict__ bsum){
  __shared__ int s[256];
  int t = threadIdx.x; int i = blockIdx.x * 256 + t;
  s[t] = (i < NN) ? deg[i] : 0;
  __syncthreads();
  for (int off = 128; off > 0; off >>= 1){
    if (t < off) s[t] += s[t + off];
    __syncthreads();
  }
  if (t == 0) bsum[blockIdx.x] = s[0];
}

__global__ void scan2_kernel(int* bsum, int nb){
  __shared__ int s[512];
  int t = threadIdx.x;
  int v = (t < nb) ? bsum[t] : 0;
  s[t] = v;
  __syncthreads();
  for (int off = 1; off < 512; off <<= 1){
    int x = (t >= off) ? s[t - off] : 0;
    __syncthreads();
    s[t] += x;
    __syncthreads();
  }
  if (t < nb) bsum[t] = s[t] - v;
}

__global__ void scan3_kernel(const int* __restrict__ deg, const int* __restrict__ bsum,
                             int* __restrict__ rs){
  __shared__ int s[256];
  int t = threadIdx.x; int i = blockIdx.x * 256 + t;
  int v = (i < NN) ? deg[i] : 0;
  s[t] = v; __syncthreads();
  for (int off = 1; off < 256; off <<= 1){
    int x = (t >= off) ? s[t - off] : 0;
    __syncthreads();
    s[t] += x;
    __syncthreads();
  }
  if (i < NN) rs[i] = bsum[blockIdx.x] + s[t] - v;
}

__global__ void fill_kernel(const int* __restrict__ src, const int* __restrict__ dst,
                            const int* __restrict__ rs, int* __restrict__ cur,
                            int* __restrict__ ssrc){
  int i = blockIdx.x * blockDim.x + threadIdx.x;
  if (i >= EE) return;
  int d = dst[i];
  int pos = atomicAdd(&cur[d], 1);
  ssrc[rs[d] + pos] = src[i];
}

// ---------------- weight prep: Wcat bf16 [128][192] ----------------
// rows 0..63  (y0):  k<128 -> Wl0[n][k],      k>=128 -> 0
// rows 64..127(re0): k<128 -> Wr0[n-64][k],   k>=128 -> We0[n-64][k-128]
__global__ void prep_wcat_kernel(const float* __restrict__ Wl0, const float* __restrict__ Wr0,
                                 const float* __restrict__ We0, unsigned short* __restrict__ wcat){
  int idx = blockIdx.x * blockDim.x + threadIdx.x;
  if (idx >= 128 * 192) return;
  int n = idx / 192, k = idx % 192;
  float v;
  if (n < 64) v = (k < 128) ? Wl0[n * 128 + k] : 0.f;
  else        v = (k < 128) ? Wr0[(n - 64) * 128 + k] : We0[(n - 64) * 64 + (k - 128)];
  wcat[idx] = f2bf(v);
}

// ---------------- weight prep: wee = We1@We0 [16][64], b1e = We1@be0 + be1 [16] ----------------
__global__ void prep_we_kernel(const float* __restrict__ We1, const float* __restrict__ We0,
                               const float* __restrict__ be0, const float* __restrict__ be1,
                               float* __restrict__ wee, float* __restrict__ b1e){
  int idx = blockIdx.x * blockDim.x + threadIdx.x;
  if (idx < 16 * 64){
    int i = idx >> 6, j = idx & 63;
    float s = 0.f;
    for (int k = 0; k < 64; k++) s += We1[i * 64 + k] * We0[k * 64 + j];
    wee[idx] = s;
  } else if (idx < 16 * 64 + 16){
    int i = idx - 16 * 64;
    float s = be1[i];
    for (int k = 0; k < 64; k++) s += We1[i * 64 + k] * be0[k];
    b1e[i] = s;
  }
}

// ---------------- layer-0 fused MFMA GEMM ----------------
// A_ext = [x_feat | e]  (M x 192, bf16 staged), Wcat (128 x 192 bf16)
// cols 0..63 -> y0 (bf16), cols 64..127 -> re0 (fp32)
__global__ __launch_bounds__(256) void l0_gemm_kernel(
    const float* __restrict__ x_feat, const float* __restrict__ e_buf,
    const unsigned short* __restrict__ wcat,
    unsigned short* __restrict__ y0, float* __restrict__ re0, int M){
  __shared__ unsigned short As[64 * 200];   // 64 rows x (192 + 8 pad) bf16 = 25.6 KB
  const int t = threadIdx.x;
  const int row0 = blockIdx.x * 64;
  // stage A: coalesced fp32 loads, convert to bf16
  for (int idx = t; idx < 64 * 48; idx += 256){
    int r = idx / 48, q = idx % 48;          // q = float4 index within 192 floats
    int row = row0 + r;
    float4 v = make_float4(0.f, 0.f, 0.f, 0.f);
    if (row < M){
      if (q < 32) v = ((const float4*)x_feat)[(size_t)row * 32 + q];
      else        v = ((const float4*)e_buf)[(size_t)row * 16 + (q - 32)];
    }
    ushort4 u; u.x = f2bf(v.x); u.y = f2bf(v.y); u.z = f2bf(v.z); u.w = f2bf(v.w);
    *(ushort4*)&As[r * 200 + q * 4] = u;
  }
  const int w = t >> 6, l = t & 63;
  const int lm = l & 15, quad = l >> 4;
  // B fragments: wave w covers output cols 32w..32w+31 (2 col-tiles), L2-resident
  bf16x8 bfr[2][6];
  #pragma unroll
  for (int ct = 0; ct < 2; ct++){
    int n = (w * 2 + ct) * 16 + lm;
    #pragma unroll
    for (int ks = 0; ks < 6; ks++)
      bfr[ct][ks] = *(const bf16x8*)&wcat[n * 192 + ks * 32 + quad * 8];
  }
  __syncthreads();
  for (int rg = 0; rg < 4; rg++){
    bf16x8 af[6];
    #pragma unroll
    for (int ks = 0; ks < 6; ks++)
      af[ks] = *(const bf16x8*)&As[(rg * 16 + lm) * 200 + ks * 32 + quad * 8];
    f32x4 acc0 = {0.f, 0.f, 0.f, 0.f};
    f32x4 acc1 = {0.f, 0.f, 0.f, 0.f};
    #pragma unroll
    for (int ks = 0; ks < 6; ks++){
      acc0 = __builtin_amdgcn_mfma_f32_16x16x32_bf16(af[ks], bfr[0][ks], acc0, 0, 0, 0);
      acc1 = __builtin_amdgcn_mfma_f32_16x16x32_bf16(af[ks], bfr[1][ks], acc1, 0, 0, 0);
    }
    // C/D layout: col = lm, row = quad*4 + r
    #pragma unroll
    for (int r = 0; r < 4; r++){
      int grow = row0 + rg * 16 + quad * 4 + r;
      if (grow < M){
        if (w < 2){
          y0[(size_t)grow * 64 + w * 32 + lm]      = f2bf(acc0[r]);
          y0[(size_t)grow * 64 + w * 32 + 16 + lm] = f2bf(acc1[r]);
        } else {
          re0[(size_t)grow * 64 + (w - 2) * 32 + lm]      = acc0[r];
          re0[(size_t)grow * 64 + (w - 2) * 32 + 16 + lm] = acc1[r];
        }
      }
    }
  }
}

// ---------------- layer-0 aggregation: bf16 gather, 16 lanes/node, unroll 4 ----------------
__global__ void agg0_kernel(const unsigned short* __restrict__ y0,
                            const float4* __restrict__ re0,
                            const float* __restrict__ bl0, const float* __restrict__ be0,
                            const int* __restrict__ rs, const int* __restrict__ deg,
                            const int* __restrict__ ssrc, float4* __restrict__ h){
  int g = blockIdx.x * blockDim.x + threadIdx.x;
  if (g >= NN * 16) return;
  int node = g >> 4, lane = g & 15;
  int start = rs[node], cnt = deg[node];
  float acc[4][4] = {};
  int i = 0;
  for (; i + 4 <= cnt; i += 4){
    int s0 = ssrc[start + i + 0], s1 = ssrc[start + i + 1];
    int s2 = ssrc[start + i + 2], s3 = ssrc[start + i + 3];
    ushort4 v0 = *(const ushort4*)&y0[(size_t)s0 * 64 + lane * 4];
    ushort4 v1 = *(const ushort4*)&y0[(size_t)s1 * 64 + lane * 4];
    ushort4 v2 = *(const ushort4*)&y0[(size_t)s2 * 64 + lane * 4];
    ushort4 v3 = *(const ushort4*)&y0[(size_t)s3 * 64 + lane * 4];
    acc[0][0] += bf2f(v0.x); acc[0][1] += bf2f(v0.y); acc[0][2] += bf2f(v0.z); acc[0][3] += bf2f(v0.w);
    acc[1][0] += bf2f(v1.x); acc[1][1] += bf2f(v1.y); acc[1][2] += bf2f(v1.z); acc[1][3] += bf2f(v1.w);
    acc[2][0] += bf2f(v2.x); acc[2][1] += bf2f(v2.y); acc[2][2] += bf2f(v2.z); acc[2][3] += bf2f(v2.w);
    acc[3][0] += bf2f(v3.x); acc[3][1] += bf2f(v3.y); acc[3][2] += bf2f(v3.z); acc[3][3] += bf2f(v3.w);
  }
  for (; i < cnt; i++){
    int s = ssrc[start + i];
    ushort4 v = *(const ushort4*)&y0[(size_t)s * 64 + lane * 4];
    acc[0][0] += bf2f(v.x); acc[0][1] += bf2f(v.y); acc[0][2] += bf2f(v.z); acc[0][3] += bf2f(v.w);
  }
  float sx = (acc[0][0] + acc[1][0]) + (acc[2][0] + acc[3][0]);
  float sy = (acc[0][1] + acc[1][1]) + (acc[2][1] + acc[3][1]);
  float sz = (acc[0][2] + acc[1][2]) + (acc[2][2] + acc[3][2]);
  float sw = (acc[0][3] + acc[1][3]) + (acc[2][3] + acc[3][3]);
  float inv = 1.0f / (float)(cnt > 1 ? cnt : 1);
  float4 rr = re0[(size_t)node * 16 + lane];
  float4 b1 = ((const float4*)bl0)[lane];
  float4 b2 = ((const float4*)be0)[lane];
  float4 v;
  v.x = sx * inv + rr.x + b1.x + b2.x;
  v.y = sy * inv + rr.y + b1.y + b2.y;
  v.z = sz * inv + rr.z + b1.z + b2.z;
  v.w = sw * inv + rr.w + b1.w + b2.w;
  v.x = v.x > 0.f ? v.x : 0.f;
  v.y = v.y > 0.f ? v.y : 0.f;
  v.z = v.z > 0.f ? v.z : 0.f;
  v.w = v.w > 0.f ? v.w : 0.f;
  h[(size_t)node * 16 + lane] = v;
}

// ---------- dual 16-col GEMM: Y1 = H@Wl1^T ; Out = H@Wr1^T + E@Wee^T + bl1 + b1e ----------
__global__ __launch_bounds__(256) void gemm16_dual_kernel(
    const float* __restrict__ H, const float* __restrict__ E,
    const float* __restrict__ Wl1, const float* __restrict__ Wr1, const float* __restrict__ Wee,
    const float* __restrict__ bl1, const float* __restrict__ b1e,
    float* __restrict__ Y1, float* __restrict__ Out, int M){
  __shared__ float Hs[64][65];
  __shared__ float Es[64][65];
  __shared__ float Wls[16][65];
  __shared__ float Wrs[16][65];
  __shared__ float Wes[16][65];
  __shared__ float bs[16];
  const int t = threadIdx.x;
  const int row0 = blockIdx.x * 64;
  {
    int j = t >> 4, kq = t & 15;
    float4 a = ((const float4*)Wl1)[j * 16 + kq];
    float4 b = ((const float4*)Wr1)[j * 16 + kq];
    float4 c = ((const float4*)Wee)[j * 16 + kq];
    Wls[j][kq*4+0]=a.x; Wls[j][kq*4+1]=a.y; Wls[j][kq*4+2]=a.z; Wls[j][kq*4+3]=a.w;
    Wrs[j][kq*4+0]=b.x; Wrs[j][kq*4+1]=b.y; Wrs[j][kq*4+2]=b.z; Wrs[j][kq*4+3]=b.w;
    Wes[j][kq*4+0]=c.x; Wes[j][kq*4+1]=c.y; Wes[j][kq*4+2]=c.z; Wes[j][kq*4+3]=c.w;
  }
  if (t < 16) bs[t] = bl1[t] + b1e[t];
  for (int idx = t; idx < 64 * 16; idx += 256){
    int n = idx >> 4, kq = idx & 15;
    int row = row0 + n;
    float4 v = make_float4(0.f,0.f,0.f,0.f), u = make_float4(0.f,0.f,0.f,0.f);
    if (row < M){
      v = ((const float4*)H)[(size_t)row * 16 + kq];
      u = ((const float4*)E)[(size_t)row * 16 + kq];
    }
    Hs[n][kq*4+0]=v.x; Hs[n][kq*4+1]=v.y; Hs[n][kq*4+2]=v.z; Hs[n][kq*4+3]=v.w;
    Es[n][kq*4+0]=u.x; Es[n][kq*4+1]=u.y; Es[n][kq*4+2]=u.z; Es[n][kq*4+3]=u.w;
  }
  __syncthreads();
  const int n = t >> 2, jq = t & 3;
  float y[4] = {}, o[4] = {};
  #pragma unroll 4
  for (int k = 0; k < 64; k++){
    float a = Hs[n][k];
    float e = Es[n][k];
    #pragma unroll
    for (int j = 0; j < 4; j++){
      y[j] = fmaf(a, Wls[jq*4 + j][k], y[j]);
      o[j] = fmaf(a, Wrs[jq*4 + j][k], o[j]);
      o[j] = fmaf(e, Wes[jq*4 + j][k], o[j]);
    }
  }
  int row = row0 + n;
  if (row < M){
    ((float4*)Y1)[(size_t)row * 4 + jq] = make_float4(y[0], y[1], y[2], y[3]);
    ((float4*)Out)[(size_t)row * 4 + jq] =
        make_float4(o[0] + bs[jq*4+0], o[1] + bs[jq*4+1], o[2] + bs[jq*4+2], o[3] + bs[jq*4+3]);
  }
}

// ---------------- layer-1 aggregation: 4 lanes/node (float4), unroll 2 ----------------
__global__ void agg1_kernel(const float4* __restrict__ y1, const int* __restrict__ rs,
                            const int* __restrict__ deg, const int* __restrict__ ssrc,
                            float4* __restrict__ outp){
  int g = blockIdx.x * blockDim.x + threadIdx.x;
  if (g >= NN * 4) return;
  int node = g >> 2, lane = g & 3;
  int start = rs[node], cnt = deg[node];
  float4 a0 = make_float4(0.f,0.f,0.f,0.f), a1 = a0;
  int i = 0;
  for (; i + 2 <= cnt; i += 2){
    int s0 = ssrc[start+i+0], s1 = ssrc[start+i+1];
    float4 v0 = y1[(size_t)s0 * 4 + lane];
    float4 v1 = y1[(size_t)s1 * 4 + lane];
    a0.x += v0.x; a0.y += v0.y; a0.z += v0.z; a0.w += v0.w;
    a1.x += v1.x; a1.y += v1.y; a1.z += v1.z; a1.w += v1.w;
  }
  if (i < cnt){
    int s = ssrc[start + i];
    float4 v = y1[(size_t)s * 4 + lane];
    a0.x += v.x; a0.y += v.y; a0.z += v.z; a0.w += v.w;
  }
  float inv = 1.0f / (float)(cnt > 1 ? cnt : 1);
  float4 o = outp[(size_t)node * 4 + lane];
  o.x += (a0.x + a1.x) * inv;
  o.y += (a0.y + a1.y) * inv;
  o.z += (a0.z + a1.z) * inv;
  o.w += (a0.w + a1.w) * inv;
  outp[(size_t)node * 4 + lane] = o;
}

extern "C" void kernel_launch(void* const* d_in, const int* in_sizes, int n_in,
                              void* d_out, int out_size, void* d_ws, size_t ws_size,
                              hipStream_t stream){
  (void)in_sizes; (void)n_in; (void)out_size; (void)ws_size;
  const float* x_feat = (const float*)d_in[0];
  const float* x_emb  = (const float*)d_in[1];
  const int*   ei     = (const int*)d_in[2];
  const float* Wl0 = (const float*)d_in[3];
  const float* bl0 = (const float*)d_in[4];
  const float* Wr0 = (const float*)d_in[5];
  const float* We0 = (const float*)d_in[6];
  const float* be0 = (const float*)d_in[7];
  const float* Wl1 = (const float*)d_in[8];
  const float* bl1 = (const float*)d_in[9];
  const float* Wr1 = (const float*)d_in[10];
  const float* We1 = (const float*)d_in[11];
  const float* be1 = (const float*)d_in[12];
  float* out = (float*)d_out;

  // workspace layout (~96 MB)
  char* w = (char*)d_ws;
  float* e_buf = (float*)w;          w += sizeof(float) * (size_t)NN * 64;
  float* h     = (float*)w;          w += sizeof(float) * (size_t)NN * 64;
  float* re0   = (float*)w;          w += sizeof(float) * (size_t)NN * 64;
  unsigned short* y0 = (unsigned short*)w;  w += sizeof(unsigned short) * (size_t)NN * 64;
  float* y1    = (float*)w;          w += sizeof(float) * (size_t)NN * 16;
  unsigned short* wcat = (unsigned short*)w; w += sizeof(unsigned short) * 128 * 192;
  float* wee   = (float*)w;          w += sizeof(float) * 16 * 64;
  float* b1e   = (float*)w;          w += sizeof(float) * 16;
  int* deg     = (int*)w;            w += sizeof(int) * NN;
  int* rs      = (int*)w;            w += sizeof(int) * NN;
  int* cur     = (int*)w;            w += sizeof(int) * NN;
  int* bsum    = (int*)w;            w += sizeof(int) * 1024;
  int* ssrc    = (int*)w;            w += sizeof(int) * (size_t)EE;

  const int* srcp = ei;
  const int* dstp = ei + EE;

  hipMemsetAsync(deg, 0, sizeof(int) * NN, stream);
  hipMemsetAsync(cur, 0, sizeof(int) * NN, stream);

  compute_e_kernel<<<ceil_div(NN * 16, 256), 256, 0, stream>>>(x_emb, e_buf);
  deg_kernel<<<ceil_div(EE, 256), 256, 0, stream>>>(dstp, deg);
  int nb = ceil_div(NN, 256);   // 391
  scan1_kernel<<<nb, 256, 0, stream>>>(deg, bsum);
  scan2_kernel<<<1, 512, 0, stream>>>(bsum, nb);
  scan3_kernel<<<nb, 256, 0, stream>>>(deg, bsum, rs);
  fill_kernel<<<ceil_div(EE, 256), 256, 0, stream>>>(srcp, dstp, rs, cur, ssrc);

  // weight prep (tiny)
  prep_wcat_kernel<<<ceil_div(128 * 192, 256), 256, 0, stream>>>(Wl0, Wr0, We0, wcat);
  prep_we_kernel<<<5, 256, 0, stream>>>(We1, We0, be0, be1, wee, b1e);

  // layer 0: y0 = bf16(x@Wl0^T), re0 = x@Wr0^T + e@We0^T   (one fused MFMA pass)
  l0_gemm_kernel<<<ceil_div(NN, 64), 256, 0, stream>>>(x_feat, e_buf, wcat, y0, re0, NN);

  // h = relu(agg(y0)/deg + re0 + bl0 + be0)
  agg0_kernel<<<ceil_div(NN * 16, 256), 256, 0, stream>>>(
      y0, (const float4*)re0, bl0, be0, rs, deg, ssrc, (float4*)h);

  // layer 1: y1 = h@Wl1^T ; out = h@Wr1^T + e@(We1·We0)^T + bl1 + (We1·be0 + be1)
  gemm16_dual_kernel<<<ceil_div(NN, 64), 256, 0, stream>>>(h, e_buf, Wl1, Wr1, wee,
                                                           bl1, b1e, y1, out, NN);
  agg1_kernel<<<ceil_div(NN * 4, 256), 256, 0, stream>>>(
      (const float4*)y1, rs, deg, ssrc, (float4*)out);
}